// Round 9
// baseline (635.660 us; speedup 1.0000x reference)
//
#include <hip/hip_runtime.h>
#include <stdint.h>

#define VOCAB 50257
#define NP    50304      // padded vocab = 393*128
#define H     256
#define BS    4096       // B*S tokens
#define K3    256        // single-f16 K (A-rounding ~= B-rounding ~5e-4 each)
#define SIB   0.0625f    // 1/sqrt(256)

typedef __attribute__((ext_vector_type(8))) _Float16 f16x8;
typedef __attribute__((ext_vector_type(4))) float f32x4;

__device__ __forceinline__ void gload_lds16(const void* g, void* l) {
  __builtin_amdgcn_global_load_lds(
      (const __attribute__((address_space(1))) void*)g,
      (__attribute__((address_space(3))) void*)l, 16, 0, 0);
}

// ---------------- sib projections: polW@sib0, polW@sib1, childW@sib0, childW@sib1
__global__ __launch_bounds__(256) void k_sib(const float* __restrict__ pol_W1,
                                             const float* __restrict__ child_W,
                                             const float* __restrict__ sib_emb,
                                             float* __restrict__ sibproj) {
  const int b = blockIdx.x;  // 0..3
  const float* Wm = (b < 2) ? pol_W1 : child_W;
  const float* v = sib_emb + (b & 1) * H;
  const int h = threadIdx.x;
  const float4* wr = (const float4*)(Wm + h * H);
  const float4* vr = (const float4*)v;
  float acc = 0.f;
  for (int i = 0; i < 64; ++i) {
    float4 w = wr[i], x = vr[i];
    acc += w.x * x.x + w.y * x.y + w.z * x.z + w.w * x.w;
  }
  sibproj[b * H + h] = acc;
}

// ---------------- out_W f32 -> f16 [NP][256] (pad rows zero)
__global__ __launch_bounds__(256) void k_conv(const float* __restrict__ W,
                                              _Float16* __restrict__ B2) {
  const int64_t nit = (int64_t)NP * 32;  // 8 f16 per iter
  for (int64_t i = (int64_t)blockIdx.x * blockDim.x + threadIdx.x; i < nit;
       i += (int64_t)gridDim.x * blockDim.x) {
    const int v = (int)(i >> 5);
    const int h8 = ((int)i & 31) * 8;
    float4 w0, w1;
    if (v < VOCAB) {
      w0 = *(const float4*)(W + (int64_t)v * H + h8);
      w1 = *(const float4*)(W + (int64_t)v * H + h8 + 4);
    } else {
      w0 = make_float4(0.f, 0.f, 0.f, 0.f);
      w1 = w0;
    }
    _Float16 o[8] = {(_Float16)w0.x, (_Float16)w0.y, (_Float16)w0.z, (_Float16)w0.w,
                     (_Float16)w1.x, (_Float16)w1.y, (_Float16)w1.z, (_Float16)w1.w};
    *(f16x8*)(B2 + (int64_t)v * K3 + h8) = *(f16x8*)o;
  }
}

// ---------------- per-token tree -> pooled -> A2 (f16 [4096][256])
#define MATVEC(Wp, SRC, ACC)                                                      \
  do {                                                                            \
    _Pragma("unroll") for (int j = 0; j < 4; ++j)                                 \
        _Pragma("unroll") for (int tt = 0; tt < 4; ++tt) ACC[j][tt] = 0.f;        \
    _Pragma("unroll 2") for (int e4 = 0; e4 < 64; ++e4) {                         \
      float4 wv[4], sv[4];                                                        \
      _Pragma("unroll") for (int j = 0; j < 4; ++j)                               \
          wv[j] = *(const float4*)(Wp + (hg + 64 * j) * H + e4 * 4);              \
      _Pragma("unroll") for (int tt = 0; tt < 4; ++tt)                            \
          sv[tt] = *(const float4*)&SRC[tg * 4 + tt][e4 * 4];                     \
      _Pragma("unroll") for (int j = 0; j < 4; ++j)                               \
          _Pragma("unroll") for (int tt = 0; tt < 4; ++tt)                        \
              ACC[j][tt] += wv[j].x * sv[tt].x + wv[j].y * sv[tt].y +             \
                            wv[j].z * sv[tt].z + wv[j].w * sv[tt].w;              \
    }                                                                             \
  } while (0)

#define REDUCE_TO_X(slot)                                                \
  do {                                                                   \
    const int rt = tid >> 4, rl = tid & 15;                              \
    float part = 0.f;                                                    \
    _Pragma("unroll") for (int i = 0; i < 16; ++i) part +=               \
        ZW[rt][rl + 16 * i];                                             \
    part += __shfl_xor(part, 1, 16);                                     \
    part += __shfl_xor(part, 2, 16);                                     \
    part += __shfl_xor(part, 4, 16);                                     \
    part += __shfl_xor(part, 8, 16);                                     \
    if (rl == 0) X[slot][rt] = part + b2;                                \
  } while (0)

__global__ __launch_bounds__(256) void k_pooled(
    const int* __restrict__ tokens, const float* __restrict__ emb,
    const float* __restrict__ proj_W, const float* __restrict__ proj_b,
    const float* __restrict__ child_W, const float* __restrict__ child_b,
    const float* __restrict__ sib_emb, const float* __restrict__ depth_emb,
    const float* __restrict__ pol_W1, const float* __restrict__ pol_b1,
    const float* __restrict__ pol_w2, const float* __restrict__ pol_b2,
    const float* __restrict__ sibproj, _Float16* __restrict__ A2) {
  __shared__ float IN[16][256];
  __shared__ float H0[16][256];
  __shared__ float B0s[16][256];
  __shared__ float ZW[16][264];
  __shared__ float X[3][16];
  __shared__ int TOK[16];
  const int tid = threadIdx.x;
  const int hg = tid & 63;   // h = hg + 64*j
  const int tg = tid >> 6;   // tokens tg*4 .. tg*4+3
  const int t0 = blockIdx.x * 16;
  const float b2 = pol_b2[0];

  float sibs[4];
#pragma unroll
  for (int j = 0; j < 4; ++j) {
    const int hj = hg + 64 * j;
    sibs[j] = SIB * (sib_emb[hj] + sib_emb[H + hj]);
  }

  if (tid < 16) TOK[tid] = tokens[t0 + tid];
  __syncthreads();
  for (int t = 0; t < 16; ++t) IN[t][tid] = emb[(int64_t)TOK[t] * H + tid];
  __syncthreads();

  float acc[4][4], sum[4][4];

  // h0 = proj_W @ emb + proj_b
  MATVEC(proj_W, IN, acc);
#pragma unroll
  for (int j = 0; j < 4; ++j) {
    const int hj = hg + 64 * j;
    const float pb = proj_b[hj];
#pragma unroll
    for (int tt = 0; tt < 4; ++tt) {
      const float h0v = acc[j][tt] + pb;
      H0[tg * 4 + tt][hj] = h0v;
      sum[j][tt] = h0v;
    }
  }
  __syncthreads();

  // depth-0 policy
  MATVEC(pol_W1, H0, acc);
#pragma unroll
  for (int j = 0; j < 4; ++j) {
    const int hj = hg + 64 * j;
    const float pb1 = pol_b1[hj], de0 = depth_emb[hj], w2 = pol_w2[hj];
#pragma unroll
    for (int tt = 0; tt < 4; ++tt) {
      const float z = tanhf(acc[j][tt] + pb1 + de0);
      ZW[tg * 4 + tt][hj] = z * w2;
    }
  }
  __syncthreads();
  REDUCE_TO_X(0);
  __syncthreads();

  // depth-0 children base
  MATVEC(child_W, H0, acc);
#pragma unroll
  for (int j = 0; j < 4; ++j) {
    const int hj = hg + 64 * j;
    const float cb = child_b[hj];
#pragma unroll
    for (int tt = 0; tt < 4; ++tt) {
      const float base0 = tanhf(acc[j][tt] + cb);
      B0s[tg * 4 + tt][hj] = base0;
      const float g0 = (X[0][tg * 4 + tt] >= 0.f) ? 1.f : 0.f;
      sum[j][tt] += g0 * (2.f * base0 + sibs[j]);
    }
  }
  __syncthreads();

  // depth-1 policy: polW@base (+ precomputed polW@sib_k)
  float accP[4][4];
  MATVEC(pol_W1, B0s, accP);
#pragma unroll
  for (int k = 0; k < 2; ++k) {
#pragma unroll
    for (int j = 0; j < 4; ++j) {
      const int hj = hg + 64 * j;
      const float pb1 = pol_b1[hj], de1 = depth_emb[H + hj], w2 = pol_w2[hj];
      const float ps = sibproj[k * H + hj];
#pragma unroll
      for (int tt = 0; tt < 4; ++tt) {
        const float z = tanhf(accP[j][tt] + SIB * ps + pb1 + de1);
        ZW[tg * 4 + tt][hj] = z * w2;
      }
    }
    __syncthreads();
    if (k == 0) REDUCE_TO_X(1); else REDUCE_TO_X(2);
    __syncthreads();
  }

  // depth-1 children base + final pooled
  MATVEC(child_W, B0s, acc);
#pragma unroll
  for (int j = 0; j < 4; ++j) {
    const int hj = hg + 64 * j;
    const float cb = child_b[hj];
    const float cs0 = sibproj[2 * H + hj], cs1 = sibproj[3 * H + hj];
#pragma unroll
    for (int tt = 0; tt < 4; ++tt) {
      const int t = tg * 4 + tt;
      const float g0 = (X[0][t] >= 0.f) ? 1.f : 0.f;
      const float m0 = (g0 > 0.f && X[1][t] >= 0.f) ? 1.f : 0.f;
      const float m1 = (g0 > 0.f && X[2][t] >= 0.f) ? 1.f : 0.f;
      const float bk0 = tanhf(acc[j][tt] + SIB * cs0 + cb);
      const float bk1 = tanhf(acc[j][tt] + SIB * cs1 + cb);
      float s = sum[j][tt] + m0 * (2.f * bk0 + sibs[j]) + m1 * (2.f * bk1 + sibs[j]);
      const float cnt = 1.f + 2.f * g0 + 2.f * (m0 + m1);
      const float pooled = s / (cnt + 1e-8f);
      A2[(int64_t)(t0 + t) * K3 + hj] = (_Float16)pooled;
    }
  }
}

// ---------------- big GEMM: C[4096][50257] = A2[4096][256] * B2[50304][256]^T + out_b
// R8 skeleton unchanged except ONE variable: epilogue stores are PLAIN (not
// nontemporal). Theory: C row pitch 201028B (==4 mod 64) makes every 512B
// segment straddle 2 partial cache lines; nt marked them evict-first so they
// flushed before the n-adjacent block completed the line -> HBM RMW (measured
// WRITE 1.3-1.6x ideal in R1/R2). Plain stores let partial lines merge in L2.
__global__ __launch_bounds__(256) void k_gemm(const _Float16* __restrict__ A2,
                                              const _Float16* __restrict__ B2,
                                              const float* __restrict__ out_b,
                                              float* __restrict__ C) {
  __shared__ __align__(16) char smem[65536];  // 2 x (At 16KB + Bt 16KB)
  const int tid = threadIdx.x;
  const int lane = tid & 63;
  const int w = tid >> 6;
  const int wg = blockIdx.x;
  const int xcd = wg & 7;
  const int local = wg >> 3;  // [0,1572)
  int gl;
  if (local < 1568) {
    const int mhalf = local / 784;  // 784 = 16*49
    const int r = local % 784;
    const int n_l = r >> 4;   // 0..48
    const int m_in = r & 15;
    gl = n_l * 32 + mhalf * 16 + m_in;
  } else {
    gl = local;
  }
  const int idx = xcd * 1572 + gl;
  const int m0 = (idx & 31) * 128;
  const int n0 = (idx >> 5) * 128;
  f32x4 acc[4][4] = {};

  // staging geometry: per instr a wave writes 8 rows x 64 f16 (1KB linear).
  const int rl = lane >> 3;                 // row within 8-row group
  const int gsw = (lane & 7) ^ rl;          // pre-swizzled source granule
  const _Float16* gA = A2 + (int64_t)(m0 + w * 32 + rl) * K3 + gsw * 8;
  const _Float16* gB = B2 + (int64_t)(n0 + w * 32 + rl) * K3 + gsw * 8;

  const int fr = lane & 15;
  const int g = lane >> 4;                  // K-octet within 32-wide MFMA K
  const int am = (w >> 1) * 64;
  const int bn = (w & 1) * 64;

#define STAGE(c, t)                                                          \
  do {                                                                       \
    _Pragma("unroll") for (int q = 0; q < 4; ++q) {                          \
      gload_lds16(gA + (int64_t)q * 8 * K3 + (t) * 64,                       \
                  (_Float16*)(smem + (c) * 32768) + (w * 32 + q * 8) * 64);  \
      gload_lds16(gB + (int64_t)q * 8 * K3 + (t) * 64,                       \
                  (_Float16*)(smem + (c) * 32768 + 16384) +                  \
                      (w * 32 + q * 8) * 64);                                \
    }                                                                        \
  } while (0)

  STAGE(0, 0);  // 8 loads/thread outstanding

  for (int t = 0; t < 4; ++t) {
    const int cur = t & 1;
    if (t < 3) {
      STAGE(cur ^ 1, t + 1);  // +8 -> 16 outstanding
      asm volatile("s_waitcnt vmcnt(8)" ::: "memory");  // stage(t) complete
    } else {
      asm volatile("s_waitcnt vmcnt(0)" ::: "memory");
    }
    __builtin_amdgcn_s_barrier();          // all waves' stage(t) visible
    __builtin_amdgcn_sched_barrier(0);
    const _Float16* At = (const _Float16*)(smem + cur * 32768);
    const _Float16* Bt = (const _Float16*)(smem + cur * 32768 + 16384);
#pragma unroll
    for (int kk = 0; kk < 2; ++kk) {
      f16x8 af[4], bf[4];
#pragma unroll
      for (int i = 0; i < 4; ++i)
        af[i] = *(const f16x8*)(At + (am + i * 16 + fr) * 64 +
                                (((kk * 4 + g) ^ (fr & 7)) * 8));
#pragma unroll
      for (int i = 0; i < 4; ++i)
        bf[i] = *(const f16x8*)(Bt + (bn + i * 16 + fr) * 64 +
                                (((kk * 4 + g) ^ (fr & 7)) * 8));
#pragma unroll
      for (int i = 0; i < 4; ++i)
#pragma unroll
        for (int j = 0; j < 4; ++j)
          acc[i][j] = __builtin_amdgcn_mfma_f32_16x16x32_f16(af[i], bf[j], acc[i][j], 0, 0, 0);
    }
    __builtin_amdgcn_sched_barrier(0);
    __builtin_amdgcn_s_barrier();          // reads of buf[cur] done -> safe to overwrite
  }

  // ---- epilogue: per m-chunk q, transpose 32x128 f32 through LDS, stream out
  float biasj[4];
#pragma unroll
  for (int j = 0; j < 4; ++j) {
    const int gn = n0 + bn + j * 16 + fr;
    biasj[j] = (gn < VOCAB) ? out_b[gn] : 0.f;
  }
  float* L = (float*)smem;  // [32][132] padded
#pragma unroll
  for (int q = 0; q < 4; ++q) {
#pragma unroll
    for (int j = 0; j < 4; ++j) {
      const int lcol = bn + j * 16 + fr;
#pragma unroll
      for (int r = 0; r < 4; ++r) {
        const int lrow = (w >> 1) * 16 + g * 4 + r;
        L[lrow * 132 + lcol] = acc[q][j][r] + biasj[j];
      }
    }
    __syncthreads();
#pragma unroll
    for (int r8 = 0; r8 < 8; ++r8) {
      const int lr = w * 8 + r8;
      const int gm = m0 + (lr >> 4) * 64 + q * 16 + (lr & 15);
      float* Crow = C + (int64_t)gm * VOCAB + n0;
#pragma unroll
      for (int hh = 0; hh < 2; ++hh) {
        const int c = hh * 64 + lane;
        const float v = L[lr * 132 + c];
        if (n0 + c < VOCAB) Crow[c] = v;   // PLAIN store (was nontemporal)
      }
    }
    __syncthreads();
  }
#undef STAGE
}

extern "C" void kernel_launch(void* const* d_in, const int* in_sizes, int n_in,
                              void* d_out, int out_size, void* d_ws, size_t ws_size,
                              hipStream_t stream) {
  const int* tokens = (const int*)d_in[0];
  const float* embedding = (const float*)d_in[1];
  const float* proj_W = (const float*)d_in[2];
  const float* proj_b = (const float*)d_in[3];
  const float* child_W = (const float*)d_in[4];
  const float* child_b = (const float*)d_in[5];
  const float* sib_emb = (const float*)d_in[6];
  const float* depth_emb = (const float*)d_in[7];
  const float* pol_W1 = (const float*)d_in[8];
  const float* pol_b1 = (const float*)d_in[9];
  const float* pol_w2 = (const float*)d_in[10];
  const float* pol_b2 = (const float*)d_in[11];
  const float* out_W = (const float*)d_in[12];
  const float* out_b = (const float*)d_in[13];
  float* C = (float*)d_out;
  char* ws = (char*)d_ws;
  _Float16* B2 = (_Float16*)ws;                              // 50304*256*2 = 25,755,648 B
  _Float16* A2 = (_Float16*)(ws + 25755648);                 // 4096*256*2  =  2,097,152 B
  float* sibproj = (float*)(ws + 25755648 + 2097152);        // 4*256*4 = 4 KB

  k_sib<<<4, 256, 0, stream>>>(pol_W1, child_W, sib_emb, sibproj);
  k_conv<<<2048, 256, 0, stream>>>(out_W, B2);
  k_pooled<<<256, 256, 0, stream>>>(tokens, embedding, proj_W, proj_b, child_W,
                                    child_b, sib_emb, depth_emb, pol_W1, pol_b1,
                                    pol_w2, pol_b2, sibproj, A2);
  k_gemm<<<12576, 256, 0, stream>>>(A2, B2, out_b, C);
}

// Round 10
// 588.100 us; speedup vs baseline: 1.0809x; 1.0809x over previous
//
#include <hip/hip_runtime.h>
#include <stdint.h>

#define VOCAB 50257
#define NP    50304      // padded vocab = 786*64
#define H     256
#define BS    4096       // B*S tokens
#define K3    256        // single-f16 K
#define SIB   0.0625f    // 1/sqrt(256)

typedef __attribute__((ext_vector_type(8))) _Float16 f16x8;
typedef __attribute__((ext_vector_type(4))) float f32x4;

__device__ __forceinline__ void gload_lds16(const void* g, void* l) {
  __builtin_amdgcn_global_load_lds(
      (const __attribute__((address_space(1))) void*)g,
      (__attribute__((address_space(3))) void*)l, 16, 0, 0);
}

// ---------------- sib projections: polW@sib0, polW@sib1, childW@sib0, childW@sib1
__global__ __launch_bounds__(256) void k_sib(const float* __restrict__ pol_W1,
                                             const float* __restrict__ child_W,
                                             const float* __restrict__ sib_emb,
                                             float* __restrict__ sibproj) {
  const int b = blockIdx.x;  // 0..3
  const float* Wm = (b < 2) ? pol_W1 : child_W;
  const float* v = sib_emb + (b & 1) * H;
  const int h = threadIdx.x;
  const float4* wr = (const float4*)(Wm + h * H);
  const float4* vr = (const float4*)v;
  float acc = 0.f;
  for (int i = 0; i < 64; ++i) {
    float4 w = wr[i], x = vr[i];
    acc += w.x * x.x + w.y * x.y + w.z * x.z + w.w * x.w;
  }
  sibproj[b * H + h] = acc;
}

// ---------------- out_W f32 -> f16 [NP][256] (pad rows zero)
__global__ __launch_bounds__(256) void k_conv(const float* __restrict__ W,
                                              _Float16* __restrict__ B2) {
  const int64_t nit = (int64_t)NP * 32;  // 8 f16 per iter
  for (int64_t i = (int64_t)blockIdx.x * blockDim.x + threadIdx.x; i < nit;
       i += (int64_t)gridDim.x * blockDim.x) {
    const int v = (int)(i >> 5);
    const int h8 = ((int)i & 31) * 8;
    float4 w0, w1;
    if (v < VOCAB) {
      w0 = *(const float4*)(W + (int64_t)v * H + h8);
      w1 = *(const float4*)(W + (int64_t)v * H + h8 + 4);
    } else {
      w0 = make_float4(0.f, 0.f, 0.f, 0.f);
      w1 = w0;
    }
    _Float16 o[8] = {(_Float16)w0.x, (_Float16)w0.y, (_Float16)w0.z, (_Float16)w0.w,
                     (_Float16)w1.x, (_Float16)w1.y, (_Float16)w1.z, (_Float16)w1.w};
    *(f16x8*)(B2 + (int64_t)v * K3 + h8) = *(f16x8*)o;
  }
}

// ---------------- per-token tree -> pooled -> A2 (f16 [4096][256])
#define MATVEC(Wp, SRC, ACC)                                                      \
  do {                                                                            \
    _Pragma("unroll") for (int j = 0; j < 4; ++j)                                 \
        _Pragma("unroll") for (int tt = 0; tt < 4; ++tt) ACC[j][tt] = 0.f;        \
    _Pragma("unroll 2") for (int e4 = 0; e4 < 64; ++e4) {                         \
      float4 wv[4], sv[4];                                                        \
      _Pragma("unroll") for (int j = 0; j < 4; ++j)                               \
          wv[j] = *(const float4*)(Wp + (hg + 64 * j) * H + e4 * 4);              \
      _Pragma("unroll") for (int tt = 0; tt < 4; ++tt)                            \
          sv[tt] = *(const float4*)&SRC[tg * 4 + tt][e4 * 4];                     \
      _Pragma("unroll") for (int j = 0; j < 4; ++j)                               \
          _Pragma("unroll") for (int tt = 0; tt < 4; ++tt)                        \
              ACC[j][tt] += wv[j].x * sv[tt].x + wv[j].y * sv[tt].y +             \
                            wv[j].z * sv[tt].z + wv[j].w * sv[tt].w;              \
    }                                                                             \
  } while (0)

#define REDUCE_TO_X(slot)                                                \
  do {                                                                   \
    const int rt = tid >> 4, rl = tid & 15;                              \
    float part = 0.f;                                                    \
    _Pragma("unroll") for (int i = 0; i < 16; ++i) part +=               \
        ZW[rt][rl + 16 * i];                                             \
    part += __shfl_xor(part, 1, 16);                                     \
    part += __shfl_xor(part, 2, 16);                                     \
    part += __shfl_xor(part, 4, 16);                                     \
    part += __shfl_xor(part, 8, 16);                                     \
    if (rl == 0) X[slot][rt] = part + b2;                                \
  } while (0)

__global__ __launch_bounds__(256) void k_pooled(
    const int* __restrict__ tokens, const float* __restrict__ emb,
    const float* __restrict__ proj_W, const float* __restrict__ proj_b,
    const float* __restrict__ child_W, const float* __restrict__ child_b,
    const float* __restrict__ sib_emb, const float* __restrict__ depth_emb,
    const float* __restrict__ pol_W1, const float* __restrict__ pol_b1,
    const float* __restrict__ pol_w2, const float* __restrict__ pol_b2,
    const float* __restrict__ sibproj, _Float16* __restrict__ A2) {
  __shared__ float IN[16][256];
  __shared__ float H0[16][256];
  __shared__ float B0s[16][256];
  __shared__ float ZW[16][264];
  __shared__ float X[3][16];
  __shared__ int TOK[16];
  const int tid = threadIdx.x;
  const int hg = tid & 63;   // h = hg + 64*j
  const int tg = tid >> 6;   // tokens tg*4 .. tg*4+3
  const int t0 = blockIdx.x * 16;
  const float b2 = pol_b2[0];

  float sibs[4];
#pragma unroll
  for (int j = 0; j < 4; ++j) {
    const int hj = hg + 64 * j;
    sibs[j] = SIB * (sib_emb[hj] + sib_emb[H + hj]);
  }

  if (tid < 16) TOK[tid] = tokens[t0 + tid];
  __syncthreads();
  for (int t = 0; t < 16; ++t) IN[t][tid] = emb[(int64_t)TOK[t] * H + tid];
  __syncthreads();

  float acc[4][4], sum[4][4];

  // h0 = proj_W @ emb + proj_b
  MATVEC(proj_W, IN, acc);
#pragma unroll
  for (int j = 0; j < 4; ++j) {
    const int hj = hg + 64 * j;
    const float pb = proj_b[hj];
#pragma unroll
    for (int tt = 0; tt < 4; ++tt) {
      const float h0v = acc[j][tt] + pb;
      H0[tg * 4 + tt][hj] = h0v;
      sum[j][tt] = h0v;
    }
  }
  __syncthreads();

  // depth-0 policy
  MATVEC(pol_W1, H0, acc);
#pragma unroll
  for (int j = 0; j < 4; ++j) {
    const int hj = hg + 64 * j;
    const float pb1 = pol_b1[hj], de0 = depth_emb[hj], w2 = pol_w2[hj];
#pragma unroll
    for (int tt = 0; tt < 4; ++tt) {
      const float z = tanhf(acc[j][tt] + pb1 + de0);
      ZW[tg * 4 + tt][hj] = z * w2;
    }
  }
  __syncthreads();
  REDUCE_TO_X(0);
  __syncthreads();

  // depth-0 children base
  MATVEC(child_W, H0, acc);
#pragma unroll
  for (int j = 0; j < 4; ++j) {
    const int hj = hg + 64 * j;
    const float cb = child_b[hj];
#pragma unroll
    for (int tt = 0; tt < 4; ++tt) {
      const float base0 = tanhf(acc[j][tt] + cb);
      B0s[tg * 4 + tt][hj] = base0;
      const float g0 = (X[0][tg * 4 + tt] >= 0.f) ? 1.f : 0.f;
      sum[j][tt] += g0 * (2.f * base0 + sibs[j]);
    }
  }
  __syncthreads();

  // depth-1 policy: polW@base (+ precomputed polW@sib_k)
  float accP[4][4];
  MATVEC(pol_W1, B0s, accP);
#pragma unroll
  for (int k = 0; k < 2; ++k) {
#pragma unroll
    for (int j = 0; j < 4; ++j) {
      const int hj = hg + 64 * j;
      const float pb1 = pol_b1[hj], de1 = depth_emb[H + hj], w2 = pol_w2[hj];
      const float ps = sibproj[k * H + hj];
#pragma unroll
      for (int tt = 0; tt < 4; ++tt) {
        const float z = tanhf(accP[j][tt] + SIB * ps + pb1 + de1);
        ZW[tg * 4 + tt][hj] = z * w2;
      }
    }
    __syncthreads();
    if (k == 0) REDUCE_TO_X(1); else REDUCE_TO_X(2);
    __syncthreads();
  }

  // depth-1 children base + final pooled
  MATVEC(child_W, B0s, acc);
#pragma unroll
  for (int j = 0; j < 4; ++j) {
    const int hj = hg + 64 * j;
    const float cb = child_b[hj];
    const float cs0 = sibproj[2 * H + hj], cs1 = sibproj[3 * H + hj];
#pragma unroll
    for (int tt = 0; tt < 4; ++tt) {
      const int t = tg * 4 + tt;
      const float g0 = (X[0][t] >= 0.f) ? 1.f : 0.f;
      const float m0 = (g0 > 0.f && X[1][t] >= 0.f) ? 1.f : 0.f;
      const float m1 = (g0 > 0.f && X[2][t] >= 0.f) ? 1.f : 0.f;
      const float bk0 = tanhf(acc[j][tt] + SIB * cs0 + cb);
      const float bk1 = tanhf(acc[j][tt] + SIB * cs1 + cb);
      float s = sum[j][tt] + m0 * (2.f * bk0 + sibs[j]) + m1 * (2.f * bk1 + sibs[j]);
      const float cnt = 1.f + 2.f * g0 + 2.f * (m0 + m1);
      const float pooled = s / (cnt + 1e-8f);
      A2[(int64_t)(t0 + t) * K3 + hj] = (_Float16)pooled;
    }
  }
}

// ---------------- big GEMM, n-streaming: C[4096][50257] = A2*B2^T + out_b
// Block = 64 rows x one n-group (~49 tiles of 64 cols), n-tile INNER loop.
// A (64x256 f16) in registers (loaded once). B LDS ring 2x32KB, counted-vmcnt
// 2-phase (R5-proven), granule-XOR swizzle via pre-swizzled global source.
// Per tile: K fully accumulated (8 MFMA k-steps) then stored immediately ->
// consecutive tiles write address-adjacent row segments ~1.3us apart from the
// SAME block -> plain stores line-merge in L2 (no cross-block partial lines
// except 16 group edges/row). Grid 1024 = 64 m-blocks x 16 n-groups, group
// pinned to XCD via wg&7. 4 waves/block, 2 blocks/CU.
__global__ __launch_bounds__(256) void k_gemm(const _Float16* __restrict__ A2,
                                              const _Float16* __restrict__ B2,
                                              const float* __restrict__ out_b,
                                              float* __restrict__ C) {
  __shared__ __align__(16) char smem[65536];  // 2 x 32KB B-tile ring
  const int tid = threadIdx.x;
  const int lane = tid & 63;
  const int w = tid >> 6;            // 0..3
  const int fr = lane & 15;
  const int g4 = lane >> 4;          // 0..3
  const int wg = blockIdx.x;
  const int gi = wg & 15;            // n-group (low 3 bits ~ XCD)
  const int mb = wg >> 4;            // 0..63
  const int m0 = mb * 64;
  const int tstart = gi * 49 + (gi < 2 ? gi : 2);   // 786 = 16*49 + 2
  const int cnt = 49 + (gi < 2 ? 1 : 0);

  // A-frags: 16 rows/wave, 8 k-subtiles -> 8 x f16x8 per lane (32 VGPR)
  const _Float16* aRow = A2 + (int64_t)(m0 + w * 16 + fr) * K3;
  f16x8 af[8];
#pragma unroll
  for (int kk = 0; kk < 8; ++kk)
    af[kk] = *(const f16x8*)(aRow + kk * 32 + g4 * 8);

  const int l31 = lane & 31;
  const int lrow = lane >> 5;  // 0..1

  // stage B tile tt (64 n-rows x 512B) into buf c; per instr 2 rows (1KB),
  // uniform LDS dest, granule-preswizzled source: LDS[row][q] = glob[row][q^(row&7)]
#define STAGEB(c, tt)                                                         \
  do {                                                                        \
    const int64_t nb = (int64_t)(tstart + (tt)) * 64;                         \
    _Pragma("unroll") for (int q = 0; q < 8; ++q) {                           \
      const int row = w * 16 + q * 2 + lrow;                                  \
      gload_lds16(B2 + (nb + row) * K3 + (int64_t)((l31 ^ (row & 7)) * 8),    \
                  (_Float16*)(smem + (c) * 32768) + (w * 16 + q * 2) * K3);   \
    }                                                                         \
  } while (0)

  STAGEB(0, 0);  // 8 loads/thread outstanding

  for (int tt = 0; tt < cnt; ++tt) {
    const int cur = tt & 1;
    if (tt + 1 < cnt) {
      STAGEB(cur ^ 1, tt + 1);  // -> 16 outstanding
      asm volatile("s_waitcnt vmcnt(8)" ::: "memory");  // tile tt landed
    } else {
      asm volatile("s_waitcnt vmcnt(0)" ::: "memory");
    }
    __builtin_amdgcn_s_barrier();
    __builtin_amdgcn_sched_barrier(0);

    const _Float16* Bt = (const _Float16*)(smem + cur * 32768);
    const int ntile = (tstart + tt) * 64;
    float bias[4];
#pragma unroll
    for (int ni = 0; ni < 4; ++ni) {
      const int col = ntile + ni * 16 + fr;
      bias[ni] = (col < VOCAB) ? out_b[col] : 0.f;
    }
    f32x4 acc[4] = {};
#pragma unroll
    for (int kk = 0; kk < 8; ++kk) {
      f16x8 bf[4];
#pragma unroll
      for (int ni = 0; ni < 4; ++ni)
        bf[ni] = *(const f16x8*)(Bt + (ni * 16 + fr) * K3 +
                                 (((kk * 4 + g4) ^ (fr & 7)) * 8));
#pragma unroll
      for (int ni = 0; ni < 4; ++ni)
        acc[ni] = __builtin_amdgcn_mfma_f32_16x16x32_f16(af[kk], bf[ni], acc[ni], 0, 0, 0);
    }
    __builtin_amdgcn_sched_barrier(0);
    __builtin_amdgcn_s_barrier();   // buf[cur] consumed -> next STAGEB may overwrite

    // stores (plain, after barrier; overlap next iteration's staging)
    const int mrow = m0 + w * 16 + g4 * 4;
    if (ntile + 64 <= VOCAB) {
#pragma unroll
      for (int ni = 0; ni < 4; ++ni) {
        float* cp = C + (int64_t)mrow * VOCAB + ntile + ni * 16 + fr;
        const float b = bias[ni];
#pragma unroll
        for (int r = 0; r < 4; ++r)
          cp[(int64_t)r * VOCAB] = acc[ni][r] + b;
      }
    } else {
#pragma unroll
      for (int ni = 0; ni < 4; ++ni) {
        const int col = ntile + ni * 16 + fr;
        if (col < VOCAB) {
          float* cp = C + (int64_t)mrow * VOCAB + col;
          const float b = bias[ni];
#pragma unroll
          for (int r = 0; r < 4; ++r)
            cp[(int64_t)r * VOCAB] = acc[ni][r] + b;
        }
      }
    }
  }
#undef STAGEB
}

extern "C" void kernel_launch(void* const* d_in, const int* in_sizes, int n_in,
                              void* d_out, int out_size, void* d_ws, size_t ws_size,
                              hipStream_t stream) {
  const int* tokens = (const int*)d_in[0];
  const float* embedding = (const float*)d_in[1];
  const float* proj_W = (const float*)d_in[2];
  const float* proj_b = (const float*)d_in[3];
  const float* child_W = (const float*)d_in[4];
  const float* child_b = (const float*)d_in[5];
  const float* sib_emb = (const float*)d_in[6];
  const float* depth_emb = (const float*)d_in[7];
  const float* pol_W1 = (const float*)d_in[8];
  const float* pol_b1 = (const float*)d_in[9];
  const float* pol_w2 = (const float*)d_in[10];
  const float* pol_b2 = (const float*)d_in[11];
  const float* out_W = (const float*)d_in[12];
  const float* out_b = (const float*)d_in[13];
  float* C = (float*)d_out;
  char* ws = (char*)d_ws;
  _Float16* B2 = (_Float16*)ws;                              // 50304*256*2 = 25,755,648 B
  _Float16* A2 = (_Float16*)(ws + 25755648);                 // 4096*256*2  =  2,097,152 B
  float* sibproj = (float*)(ws + 25755648 + 2097152);        // 4*256*4 = 4 KB

  k_sib<<<4, 256, 0, stream>>>(pol_W1, child_W, sib_emb, sibproj);
  k_conv<<<2048, 256, 0, stream>>>(out_W, B2);
  k_pooled<<<256, 256, 0, stream>>>(tokens, embedding, proj_W, proj_b, child_W,
                                    child_b, sib_emb, depth_emb, pol_W1, pol_b1,
                                    pol_w2, pol_b2, sibproj, A2);
  k_gemm<<<1024, 256, 0, stream>>>(A2, B2, out_b, C);
}

// Round 11
// 467.709 us; speedup vs baseline: 1.3591x; 1.2574x over previous
//
#include <hip/hip_runtime.h>
#include <stdint.h>

#define VOCAB 50257
#define NP    50304      // padded vocab = 393*128
#define H     256
#define BS    4096       // B*S tokens
#define K3    256        // single-f16 K
#define SIB   0.0625f    // 1/sqrt(256)

typedef __attribute__((ext_vector_type(8))) _Float16 f16x8;
typedef __attribute__((ext_vector_type(4))) float f32x4;

__device__ __forceinline__ void gload_lds16(const void* g, void* l) {
  __builtin_amdgcn_global_load_lds(
      (const __attribute__((address_space(1))) void*)g,
      (__attribute__((address_space(3))) void*)l, 16, 0, 0);
}

// ---------------- transpose proj_W, pol_W1, child_W -> WT[3][256][256] (WT[m][e][h])
__global__ __launch_bounds__(256) void k_tr(const float* __restrict__ pW,
                                            const float* __restrict__ qW,
                                            const float* __restrict__ cW,
                                            float* __restrict__ WT) {
  __shared__ float T[64][65];
  const int blk = blockIdx.x;           // 48 = 3 matrices x 16 tiles
  const int m = blk >> 4, t = blk & 15;
  const float* src = (m == 0) ? pW : (m == 1) ? qW : cW;
  float* dst = WT + m * 65536;
  const int tr = (t >> 2) * 64, tc = (t & 3) * 64;
  const int r = threadIdx.x >> 6, c = threadIdx.x & 63;
#pragma unroll
  for (int i = 0; i < 16; ++i) {
    const int row = r * 16 + i;
    T[row][c] = src[(tr + row) * H + tc + c];
  }
  __syncthreads();
#pragma unroll
  for (int i = 0; i < 16; ++i) {
    const int row = r * 16 + i;
    dst[(tc + row) * H + tr + c] = T[c][row];
  }
}

// ---------------- sib projections via WT (coalesced): polT@sib0/1, childT@sib0/1
__global__ __launch_bounds__(256) void k_sib(const float* __restrict__ WT,
                                             const float* __restrict__ sib_emb,
                                             float* __restrict__ sibproj) {
  const int b = blockIdx.x;  // 0..3
  const float* Wt = WT + ((b < 2) ? 65536 : 131072);
  const float* v = sib_emb + (b & 1) * H;
  const int h = threadIdx.x;
  float acc = 0.f;
  for (int e4 = 0; e4 < 64; ++e4) {
    const float4 s = *(const float4*)(v + e4 * 4);
    acc += Wt[(e4 * 4 + 0) * H + h] * s.x;
    acc += Wt[(e4 * 4 + 1) * H + h] * s.y;
    acc += Wt[(e4 * 4 + 2) * H + h] * s.z;
    acc += Wt[(e4 * 4 + 3) * H + h] * s.w;
  }
  sibproj[b * H + h] = acc;
}

// ---------------- out_W f32 -> f16 [NP][256] (pad rows zero)
__global__ __launch_bounds__(256) void k_conv(const float* __restrict__ W,
                                              _Float16* __restrict__ B2) {
  const int64_t nit = (int64_t)NP * 32;  // 8 f16 per iter
  for (int64_t i = (int64_t)blockIdx.x * blockDim.x + threadIdx.x; i < nit;
       i += (int64_t)gridDim.x * blockDim.x) {
    const int v = (int)(i >> 5);
    const int h8 = ((int)i & 31) * 8;
    float4 w0, w1;
    if (v < VOCAB) {
      w0 = *(const float4*)(W + (int64_t)v * H + h8);
      w1 = *(const float4*)(W + (int64_t)v * H + h8 + 4);
    } else {
      w0 = make_float4(0.f, 0.f, 0.f, 0.f);
      w1 = w0;
    }
    _Float16 o[8] = {(_Float16)w0.x, (_Float16)w0.y, (_Float16)w0.z, (_Float16)w0.w,
                     (_Float16)w1.x, (_Float16)w1.y, (_Float16)w1.z, (_Float16)w1.w};
    *(f16x8*)(B2 + (int64_t)v * K3 + h8) = *(f16x8*)o;
  }
}

// ---------------- per-token tree -> pooled -> A2 (f16 [4096][256])
// MATVEC_T: uses WT[e][h] -> lane h reads CONSECUTIVE addresses (1-2 lines per
// load instr) vs old per-lane row gather (64 lines per instr, est 100-160us).
#define MATVEC_T(WTp, SRC, ACC)                                                   \
  do {                                                                            \
    _Pragma("unroll") for (int j = 0; j < 4; ++j)                                 \
        _Pragma("unroll") for (int tt = 0; tt < 4; ++tt) ACC[j][tt] = 0.f;        \
    _Pragma("unroll 2") for (int e4 = 0; e4 < 64; ++e4) {                         \
      float4 s4[4];                                                               \
      _Pragma("unroll") for (int tt = 0; tt < 4; ++tt)                            \
          s4[tt] = *(const float4*)&SRC[tg * 4 + tt][e4 * 4];                     \
      _Pragma("unroll") for (int u = 0; u < 4; ++u) {                             \
        const int e = e4 * 4 + u;                                                 \
        float wt[4];                                                              \
        _Pragma("unroll") for (int j = 0; j < 4; ++j)                             \
            wt[j] = (WTp)[e * H + hg + 64 * j];                                   \
        _Pragma("unroll") for (int j = 0; j < 4; ++j)                             \
            _Pragma("unroll") for (int tt = 0; tt < 4; ++tt)                      \
                ACC[j][tt] += wt[j] * ((const float*)&s4[tt])[u];                 \
      }                                                                           \
    }                                                                             \
  } while (0)

#define REDUCE_TO_X(slot)                                                \
  do {                                                                   \
    const int rt = tid >> 4, rl = tid & 15;                              \
    float part = 0.f;                                                    \
    _Pragma("unroll") for (int i = 0; i < 16; ++i) part +=               \
        ZW[rt][rl + 16 * i];                                             \
    part += __shfl_xor(part, 1, 16);                                     \
    part += __shfl_xor(part, 2, 16);                                     \
    part += __shfl_xor(part, 4, 16);                                     \
    part += __shfl_xor(part, 8, 16);                                     \
    if (rl == 0) X[slot][rt] = part + b2;                                \
  } while (0)

__global__ __launch_bounds__(256) void k_pooled(
    const int* __restrict__ tokens, const float* __restrict__ emb,
    const float* __restrict__ WT, const float* __restrict__ proj_b,
    const float* __restrict__ child_b,
    const float* __restrict__ sib_emb, const float* __restrict__ depth_emb,
    const float* __restrict__ pol_b1,
    const float* __restrict__ pol_w2, const float* __restrict__ pol_b2,
    const float* __restrict__ sibproj, _Float16* __restrict__ A2) {
  __shared__ float IN[16][256];
  __shared__ float H0[16][256];
  __shared__ float B0s[16][256];
  __shared__ float ZW[16][264];
  __shared__ float X[3][16];
  __shared__ int TOK[16];
  const int tid = threadIdx.x;
  const int hg = tid & 63;   // h = hg + 64*j
  const int tg = tid >> 6;   // tokens tg*4 .. tg*4+3
  const int t0 = blockIdx.x * 16;
  const float b2 = pol_b2[0];
  const float* projT = WT;
  const float* polT = WT + 65536;
  const float* childT = WT + 131072;

  float sibs[4];
#pragma unroll
  for (int j = 0; j < 4; ++j) {
    const int hj = hg + 64 * j;
    sibs[j] = SIB * (sib_emb[hj] + sib_emb[H + hj]);
  }

  if (tid < 16) TOK[tid] = tokens[t0 + tid];
  __syncthreads();
  for (int t = 0; t < 16; ++t) IN[t][tid] = emb[(int64_t)TOK[t] * H + tid];
  __syncthreads();

  float acc[4][4], sum[4][4];

  // h0 = proj_W @ emb + proj_b
  MATVEC_T(projT, IN, acc);
#pragma unroll
  for (int j = 0; j < 4; ++j) {
    const int hj = hg + 64 * j;
    const float pb = proj_b[hj];
#pragma unroll
    for (int tt = 0; tt < 4; ++tt) {
      const float h0v = acc[j][tt] + pb;
      H0[tg * 4 + tt][hj] = h0v;
      sum[j][tt] = h0v;
    }
  }
  __syncthreads();

  // depth-0 policy
  MATVEC_T(polT, H0, acc);
#pragma unroll
  for (int j = 0; j < 4; ++j) {
    const int hj = hg + 64 * j;
    const float pb1 = pol_b1[hj], de0 = depth_emb[hj], w2 = pol_w2[hj];
#pragma unroll
    for (int tt = 0; tt < 4; ++tt) {
      const float z = tanhf(acc[j][tt] + pb1 + de0);
      ZW[tg * 4 + tt][hj] = z * w2;
    }
  }
  __syncthreads();
  REDUCE_TO_X(0);
  __syncthreads();

  // depth-0 children base
  MATVEC_T(childT, H0, acc);
#pragma unroll
  for (int j = 0; j < 4; ++j) {
    const int hj = hg + 64 * j;
    const float cb = child_b[hj];
#pragma unroll
    for (int tt = 0; tt < 4; ++tt) {
      const float base0 = tanhf(acc[j][tt] + cb);
      B0s[tg * 4 + tt][hj] = base0;
      const float g0 = (X[0][tg * 4 + tt] >= 0.f) ? 1.f : 0.f;
      sum[j][tt] += g0 * (2.f * base0 + sibs[j]);
    }
  }
  __syncthreads();

  // depth-1 policy: polW@base (+ precomputed polW@sib_k)
  float accP[4][4];
  MATVEC_T(polT, B0s, accP);
#pragma unroll
  for (int k = 0; k < 2; ++k) {
#pragma unroll
    for (int j = 0; j < 4; ++j) {
      const int hj = hg + 64 * j;
      const float pb1 = pol_b1[hj], de1 = depth_emb[H + hj], w2 = pol_w2[hj];
      const float ps = sibproj[k * H + hj];
#pragma unroll
      for (int tt = 0; tt < 4; ++tt) {
        const float z = tanhf(accP[j][tt] + SIB * ps + pb1 + de1);
        ZW[tg * 4 + tt][hj] = z * w2;
      }
    }
    __syncthreads();
    if (k == 0) REDUCE_TO_X(1); else REDUCE_TO_X(2);
    __syncthreads();
  }

  // depth-1 children base + final pooled
  MATVEC_T(childT, B0s, acc);
#pragma unroll
  for (int j = 0; j < 4; ++j) {
    const int hj = hg + 64 * j;
    const float cb = child_b[hj];
    const float cs0 = sibproj[2 * H + hj], cs1 = sibproj[3 * H + hj];
#pragma unroll
    for (int tt = 0; tt < 4; ++tt) {
      const int t = tg * 4 + tt;
      const float g0 = (X[0][t] >= 0.f) ? 1.f : 0.f;
      const float m0 = (g0 > 0.f && X[1][t] >= 0.f) ? 1.f : 0.f;
      const float m1 = (g0 > 0.f && X[2][t] >= 0.f) ? 1.f : 0.f;
      const float bk0 = tanhf(acc[j][tt] + SIB * cs0 + cb);
      const float bk1 = tanhf(acc[j][tt] + SIB * cs1 + cb);
      float s = sum[j][tt] + m0 * (2.f * bk0 + sibs[j]) + m1 * (2.f * bk1 + sibs[j]);
      const float cnt = 1.f + 2.f * g0 + 2.f * (m0 + m1);
      const float pooled = s / (cnt + 1e-8f);
      A2[(int64_t)(t0 + t) * K3 + hj] = (_Float16)pooled;
    }
  }
}

// ---------------- big GEMM (R8-verified, NT stores): C = A2*B2^T + out_b
__global__ __launch_bounds__(256) void k_gemm(const _Float16* __restrict__ A2,
                                              const _Float16* __restrict__ B2,
                                              const float* __restrict__ out_b,
                                              float* __restrict__ C) {
  __shared__ __align__(16) char smem[65536];  // 2 x (At 16KB + Bt 16KB)
  const int tid = threadIdx.x;
  const int lane = tid & 63;
  const int w = tid >> 6;
  const int wg = blockIdx.x;
  const int xcd = wg & 7;
  const int local = wg >> 3;  // [0,1572)
  int gl;
  if (local < 1568) {
    const int mhalf = local / 784;  // 784 = 16*49
    const int r = local % 784;
    const int n_l = r >> 4;   // 0..48
    const int m_in = r & 15;
    gl = n_l * 32 + mhalf * 16 + m_in;
  } else {
    gl = local;
  }
  const int idx = xcd * 1572 + gl;
  const int m0 = (idx & 31) * 128;
  const int n0 = (idx >> 5) * 128;
  f32x4 acc[4][4] = {};

  const int rl = lane >> 3;                 // row within 8-row group
  const int gsw = (lane & 7) ^ rl;          // pre-swizzled source granule
  const _Float16* gA = A2 + (int64_t)(m0 + w * 32 + rl) * K3 + gsw * 8;
  const _Float16* gB = B2 + (int64_t)(n0 + w * 32 + rl) * K3 + gsw * 8;

  const int fr = lane & 15;
  const int g = lane >> 4;                  // K-octet within 32-wide MFMA K
  const int am = (w >> 1) * 64;
  const int bn = (w & 1) * 64;

#define STAGE(c, t)                                                          \
  do {                                                                       \
    _Pragma("unroll") for (int q = 0; q < 4; ++q) {                          \
      gload_lds16(gA + (int64_t)q * 8 * K3 + (t) * 64,                       \
                  (_Float16*)(smem + (c) * 32768) + (w * 32 + q * 8) * 64);  \
      gload_lds16(gB + (int64_t)q * 8 * K3 + (t) * 64,                       \
                  (_Float16*)(smem + (c) * 32768 + 16384) +                  \
                      (w * 32 + q * 8) * 64);                                \
    }                                                                        \
  } while (0)

  STAGE(0, 0);  // 8 loads/thread outstanding

  for (int t = 0; t < 4; ++t) {
    const int cur = t & 1;
    if (t < 3) {
      STAGE(cur ^ 1, t + 1);  // +8 -> 16 outstanding
      asm volatile("s_waitcnt vmcnt(8)" ::: "memory");  // stage(t) complete
    } else {
      asm volatile("s_waitcnt vmcnt(0)" ::: "memory");
    }
    __builtin_amdgcn_s_barrier();          // all waves' stage(t) visible
    __builtin_amdgcn_sched_barrier(0);
    const _Float16* At = (const _Float16*)(smem + cur * 32768);
    const _Float16* Bt = (const _Float16*)(smem + cur * 32768 + 16384);
#pragma unroll
    for (int kk = 0; kk < 2; ++kk) {
      f16x8 af[4], bf[4];
#pragma unroll
      for (int i = 0; i < 4; ++i)
        af[i] = *(const f16x8*)(At + (am + i * 16 + fr) * 64 +
                                (((kk * 4 + g) ^ (fr & 7)) * 8));
#pragma unroll
      for (int i = 0; i < 4; ++i)
        bf[i] = *(const f16x8*)(Bt + (bn + i * 16 + fr) * 64 +
                                (((kk * 4 + g) ^ (fr & 7)) * 8));
#pragma unroll
      for (int i = 0; i < 4; ++i)
#pragma unroll
        for (int j = 0; j < 4; ++j)
          acc[i][j] = __builtin_amdgcn_mfma_f32_16x16x32_f16(af[i], bf[j], acc[i][j], 0, 0, 0);
    }
    __builtin_amdgcn_sched_barrier(0);
    __builtin_amdgcn_s_barrier();          // reads of buf[cur] done -> safe to overwrite
  }

  // ---- epilogue: per m-chunk q, transpose 32x128 f32 through LDS, stream out
  float biasj[4];
#pragma unroll
  for (int j = 0; j < 4; ++j) {
    const int gn = n0 + bn + j * 16 + fr;
    biasj[j] = (gn < VOCAB) ? out_b[gn] : 0.f;
  }
  float* L = (float*)smem;  // [32][132] padded
#pragma unroll
  for (int q = 0; q < 4; ++q) {
#pragma unroll
    for (int j = 0; j < 4; ++j) {
      const int lcol = bn + j * 16 + fr;
#pragma unroll
      for (int r = 0; r < 4; ++r) {
        const int lrow = (w >> 1) * 16 + g * 4 + r;
        L[lrow * 132 + lcol] = acc[q][j][r] + biasj[j];
      }
    }
    __syncthreads();
#pragma unroll
    for (int r8 = 0; r8 < 8; ++r8) {
      const int lr = w * 8 + r8;
      const int gm = m0 + (lr >> 4) * 64 + q * 16 + (lr & 15);
      float* Crow = C + (int64_t)gm * VOCAB + n0;
#pragma unroll
      for (int hh = 0; hh < 2; ++hh) {
        const int c = hh * 64 + lane;
        const float v = L[lr * 132 + c];
        if (n0 + c < VOCAB) __builtin_nontemporal_store(v, Crow + c);
      }
    }
    __syncthreads();
  }
#undef STAGE
}

extern "C" void kernel_launch(void* const* d_in, const int* in_sizes, int n_in,
                              void* d_out, int out_size, void* d_ws, size_t ws_size,
                              hipStream_t stream) {
  const int* tokens = (const int*)d_in[0];
  const float* embedding = (const float*)d_in[1];
  const float* proj_W = (const float*)d_in[2];
  const float* proj_b = (const float*)d_in[3];
  const float* child_W = (const float*)d_in[4];
  const float* child_b = (const float*)d_in[5];
  const float* sib_emb = (const float*)d_in[6];
  const float* depth_emb = (const float*)d_in[7];
  const float* pol_W1 = (const float*)d_in[8];
  const float* pol_b1 = (const float*)d_in[9];
  const float* pol_w2 = (const float*)d_in[10];
  const float* pol_b2 = (const float*)d_in[11];
  const float* out_W = (const float*)d_in[12];
  const float* out_b = (const float*)d_in[13];
  float* C = (float*)d_out;
  char* ws = (char*)d_ws;
  _Float16* B2 = (_Float16*)ws;                              // 50304*256*2 = 25,755,648 B
  _Float16* A2 = (_Float16*)(ws + 25755648);                 // 4096*256*2  =  2,097,152 B
  float* sibproj = (float*)(ws + 27852800);                  // 4 KB
  float* WT = (float*)(ws + 27856896);                       // 3*256*256*4 = 786,432 B

  k_tr<<<48, 256, 0, stream>>>(proj_W, pol_W1, child_W, WT);
  k_sib<<<4, 256, 0, stream>>>(WT, sib_emb, sibproj);
  k_conv<<<2048, 256, 0, stream>>>(out_W, B2);
  k_pooled<<<256, 256, 0, stream>>>(tokens, embedding, WT, proj_b, child_b,
                                    sib_emb, depth_emb, pol_b1,
                                    pol_w2, pol_b2, sibproj, A2);
  k_gemm<<<12576, 256, 0, stream>>>(A2, B2, out_b, C);
}

// Round 12
// 427.076 us; speedup vs baseline: 1.4884x; 1.0951x over previous
//
#include <hip/hip_runtime.h>
#include <stdint.h>

#define VOCAB 50257
#define NP    50304      // padded vocab = 393*128
#define H     256
#define BS    4096       // B*S tokens
#define K3    256        // single-f16 K
#define SIB   0.0625f    // 1/sqrt(256)

typedef __attribute__((ext_vector_type(8))) _Float16 f16x8;
typedef __attribute__((ext_vector_type(4))) float f32x4;

__device__ __forceinline__ void gload_lds16(const void* g, void* l) {
  __builtin_amdgcn_global_load_lds(
      (const __attribute__((address_space(1))) void*)g,
      (__attribute__((address_space(3))) void*)l, 16, 0, 0);
}

// ---------------- transpose proj_W, pol_W1, child_W -> WT[3][256][256] (WT[m][e][h])
__global__ __launch_bounds__(256) void k_tr(const float* __restrict__ pW,
                                            const float* __restrict__ qW,
                                            const float* __restrict__ cW,
                                            float* __restrict__ WT) {
  __shared__ float T[64][65];
  const int blk = blockIdx.x;           // 48 = 3 matrices x 16 tiles
  const int m = blk >> 4, t = blk & 15;
  const float* src = (m == 0) ? pW : (m == 1) ? qW : cW;
  float* dst = WT + m * 65536;
  const int tr = (t >> 2) * 64, tc = (t & 3) * 64;
  const int r = threadIdx.x >> 6, c = threadIdx.x & 63;
#pragma unroll
  for (int i = 0; i < 16; ++i) {
    const int row = r * 16 + i;
    T[row][c] = src[(tr + row) * H + tc + c];
  }
  __syncthreads();
#pragma unroll
  for (int i = 0; i < 16; ++i) {
    const int row = r * 16 + i;
    dst[(tc + row) * H + tr + c] = T[c][row];
  }
}

// ---------------- sib projections via WT (coalesced): polT@sib0/1, childT@sib0/1
__global__ __launch_bounds__(256) void k_sib(const float* __restrict__ WT,
                                             const float* __restrict__ sib_emb,
                                             float* __restrict__ sibproj) {
  const int b = blockIdx.x;  // 0..3
  const float* Wt = WT + ((b < 2) ? 65536 : 131072);
  const float* v = sib_emb + (b & 1) * H;
  const int h = threadIdx.x;
  float acc = 0.f;
  for (int e4 = 0; e4 < 64; ++e4) {
    const float4 s = *(const float4*)(v + e4 * 4);
    acc += Wt[(e4 * 4 + 0) * H + h] * s.x;
    acc += Wt[(e4 * 4 + 1) * H + h] * s.y;
    acc += Wt[(e4 * 4 + 2) * H + h] * s.z;
    acc += Wt[(e4 * 4 + 3) * H + h] * s.w;
  }
  sibproj[b * H + h] = acc;
}

// ---------------- out_W f32 -> f16 [NP][256] (pad rows zero)
__global__ __launch_bounds__(256) void k_conv(const float* __restrict__ W,
                                              _Float16* __restrict__ B2) {
  const int64_t nit = (int64_t)NP * 32;  // 8 f16 per iter
  for (int64_t i = (int64_t)blockIdx.x * blockDim.x + threadIdx.x; i < nit;
       i += (int64_t)gridDim.x * blockDim.x) {
    const int v = (int)(i >> 5);
    const int h8 = ((int)i & 31) * 8;
    float4 w0, w1;
    if (v < VOCAB) {
      w0 = *(const float4*)(W + (int64_t)v * H + h8);
      w1 = *(const float4*)(W + (int64_t)v * H + h8 + 4);
    } else {
      w0 = make_float4(0.f, 0.f, 0.f, 0.f);
      w1 = w0;
    }
    _Float16 o[8] = {(_Float16)w0.x, (_Float16)w0.y, (_Float16)w0.z, (_Float16)w0.w,
                     (_Float16)w1.x, (_Float16)w1.y, (_Float16)w1.z, (_Float16)w1.w};
    *(f16x8*)(B2 + (int64_t)v * K3 + h8) = *(f16x8*)o;
  }
}

// ---------------- per-token tree -> pooled -> A2 (f16 [4096][256])
#define MATVEC_T(WTp, SRC, ACC)                                                   \
  do {                                                                            \
    _Pragma("unroll") for (int j = 0; j < 4; ++j)                                 \
        _Pragma("unroll") for (int tt = 0; tt < 4; ++tt) ACC[j][tt] = 0.f;        \
    _Pragma("unroll 2") for (int e4 = 0; e4 < 64; ++e4) {                         \
      float4 s4[4];                                                               \
      _Pragma("unroll") for (int tt = 0; tt < 4; ++tt)                            \
          s4[tt] = *(const float4*)&SRC[tg * 4 + tt][e4 * 4];                     \
      _Pragma("unroll") for (int u = 0; u < 4; ++u) {                             \
        const int e = e4 * 4 + u;                                                 \
        float wt[4];                                                              \
        _Pragma("unroll") for (int j = 0; j < 4; ++j)                             \
            wt[j] = (WTp)[e * H + hg + 64 * j];                                   \
        _Pragma("unroll") for (int j = 0; j < 4; ++j)                             \
            _Pragma("unroll") for (int tt = 0; tt < 4; ++tt)                      \
                ACC[j][tt] += wt[j] * ((const float*)&s4[tt])[u];                 \
      }                                                                           \
    }                                                                             \
  } while (0)

#define REDUCE_TO_X(slot)                                                \
  do {                                                                   \
    const int rt = tid >> 4, rl = tid & 15;                              \
    float part = 0.f;                                                    \
    _Pragma("unroll") for (int i = 0; i < 16; ++i) part +=               \
        ZW[rt][rl + 16 * i];                                             \
    part += __shfl_xor(part, 1, 16);                                     \
    part += __shfl_xor(part, 2, 16);                                     \
    part += __shfl_xor(part, 4, 16);                                     \
    part += __shfl_xor(part, 8, 16);                                     \
    if (rl == 0) X[slot][rt] = part + b2;                                \
  } while (0)

__global__ __launch_bounds__(256) void k_pooled(
    const int* __restrict__ tokens, const float* __restrict__ emb,
    const float* __restrict__ WT, const float* __restrict__ proj_b,
    const float* __restrict__ child_b,
    const float* __restrict__ sib_emb, const float* __restrict__ depth_emb,
    const float* __restrict__ pol_b1,
    const float* __restrict__ pol_w2, const float* __restrict__ pol_b2,
    const float* __restrict__ sibproj, _Float16* __restrict__ A2) {
  __shared__ float IN[16][256];
  __shared__ float H0[16][256];
  __shared__ float B0s[16][256];
  __shared__ float ZW[16][264];
  __shared__ float X[3][16];
  __shared__ int TOK[16];
  const int tid = threadIdx.x;
  const int hg = tid & 63;   // h = hg + 64*j
  const int tg = tid >> 6;   // tokens tg*4 .. tg*4+3
  const int t0 = blockIdx.x * 16;
  const float b2 = pol_b2[0];
  const float* projT = WT;
  const float* polT = WT + 65536;
  const float* childT = WT + 131072;

  float sibs[4];
#pragma unroll
  for (int j = 0; j < 4; ++j) {
    const int hj = hg + 64 * j;
    sibs[j] = SIB * (sib_emb[hj] + sib_emb[H + hj]);
  }

  if (tid < 16) TOK[tid] = tokens[t0 + tid];
  __syncthreads();
  for (int t = 0; t < 16; ++t) IN[t][tid] = emb[(int64_t)TOK[t] * H + tid];
  __syncthreads();

  float acc[4][4], sum[4][4];

  // h0 = proj_W @ emb + proj_b
  MATVEC_T(projT, IN, acc);
#pragma unroll
  for (int j = 0; j < 4; ++j) {
    const int hj = hg + 64 * j;
    const float pb = proj_b[hj];
#pragma unroll
    for (int tt = 0; tt < 4; ++tt) {
      const float h0v = acc[j][tt] + pb;
      H0[tg * 4 + tt][hj] = h0v;
      sum[j][tt] = h0v;
    }
  }
  __syncthreads();

  // depth-0 policy
  MATVEC_T(polT, H0, acc);
#pragma unroll
  for (int j = 0; j < 4; ++j) {
    const int hj = hg + 64 * j;
    const float pb1 = pol_b1[hj], de0 = depth_emb[hj], w2 = pol_w2[hj];
#pragma unroll
    for (int tt = 0; tt < 4; ++tt) {
      const float z = tanhf(acc[j][tt] + pb1 + de0);
      ZW[tg * 4 + tt][hj] = z * w2;
    }
  }
  __syncthreads();
  REDUCE_TO_X(0);
  __syncthreads();

  // depth-0 children base
  MATVEC_T(childT, H0, acc);
#pragma unroll
  for (int j = 0; j < 4; ++j) {
    const int hj = hg + 64 * j;
    const float cb = child_b[hj];
#pragma unroll
    for (int tt = 0; tt < 4; ++tt) {
      const float base0 = tanhf(acc[j][tt] + cb);
      B0s[tg * 4 + tt][hj] = base0;
      const float g0 = (X[0][tg * 4 + tt] >= 0.f) ? 1.f : 0.f;
      sum[j][tt] += g0 * (2.f * base0 + sibs[j]);
    }
  }
  __syncthreads();

  // depth-1 policy: polW@base (+ precomputed polW@sib_k)
  float accP[4][4];
  MATVEC_T(polT, B0s, accP);
#pragma unroll
  for (int k = 0; k < 2; ++k) {
#pragma unroll
    for (int j = 0; j < 4; ++j) {
      const int hj = hg + 64 * j;
      const float pb1 = pol_b1[hj], de1 = depth_emb[H + hj], w2 = pol_w2[hj];
      const float ps = sibproj[k * H + hj];
#pragma unroll
      for (int tt = 0; tt < 4; ++tt) {
        const float z = tanhf(accP[j][tt] + SIB * ps + pb1 + de1);
        ZW[tg * 4 + tt][hj] = z * w2;
      }
    }
    __syncthreads();
    if (k == 0) REDUCE_TO_X(1); else REDUCE_TO_X(2);
    __syncthreads();
  }

  // depth-1 children base + final pooled
  MATVEC_T(childT, B0s, acc);
#pragma unroll
  for (int j = 0; j < 4; ++j) {
    const int hj = hg + 64 * j;
    const float cb = child_b[hj];
    const float cs0 = sibproj[2 * H + hj], cs1 = sibproj[3 * H + hj];
#pragma unroll
    for (int tt = 0; tt < 4; ++tt) {
      const int t = tg * 4 + tt;
      const float g0 = (X[0][t] >= 0.f) ? 1.f : 0.f;
      const float m0 = (g0 > 0.f && X[1][t] >= 0.f) ? 1.f : 0.f;
      const float m1 = (g0 > 0.f && X[2][t] >= 0.f) ? 1.f : 0.f;
      const float bk0 = tanhf(acc[j][tt] + SIB * cs0 + cb);
      const float bk1 = tanhf(acc[j][tt] + SIB * cs1 + cb);
      float s = sum[j][tt] + m0 * (2.f * bk0 + sibs[j]) + m1 * (2.f * bk1 + sibs[j]);
      const float cnt = 1.f + 2.f * g0 + 2.f * (m0 + m1);
      const float pooled = s / (cnt + 1e-8f);
      A2[(int64_t)(t0 + t) * K3 + hj] = (_Float16)pooled;
    }
  }
}

// ---------------- big GEMM (R8 skeleton; epilogue stores widened to dwordx4 NT)
__global__ __launch_bounds__(256) void k_gemm(const _Float16* __restrict__ A2,
                                              const _Float16* __restrict__ B2,
                                              const float* __restrict__ out_b,
                                              float* __restrict__ C) {
  __shared__ __align__(16) char smem[65536];  // 2 x (At 16KB + Bt 16KB)
  const int tid = threadIdx.x;
  const int lane = tid & 63;
  const int w = tid >> 6;
  const int wg = blockIdx.x;
  const int xcd = wg & 7;
  const int local = wg >> 3;  // [0,1572)
  int gl;
  if (local < 1568) {
    const int mhalf = local / 784;  // 784 = 16*49
    const int r = local % 784;
    const int n_l = r >> 4;   // 0..48
    const int m_in = r & 15;
    gl = n_l * 32 + mhalf * 16 + m_in;
  } else {
    gl = local;
  }
  const int idx = xcd * 1572 + gl;
  const int m0 = (idx & 31) * 128;
  const int n0 = (idx >> 5) * 128;
  f32x4 acc[4][4] = {};

  const int rl = lane >> 3;                 // row within 8-row group
  const int gsw = (lane & 7) ^ rl;          // pre-swizzled source granule
  const _Float16* gA = A2 + (int64_t)(m0 + w * 32 + rl) * K3 + gsw * 8;
  const _Float16* gB = B2 + (int64_t)(n0 + w * 32 + rl) * K3 + gsw * 8;

  const int fr = lane & 15;
  const int g = lane >> 4;                  // K-octet within 32-wide MFMA K
  const int am = (w >> 1) * 64;
  const int bn = (w & 1) * 64;

#define STAGE(c, t)                                                          \
  do {                                                                       \
    _Pragma("unroll") for (int q = 0; q < 4; ++q) {                          \
      gload_lds16(gA + (int64_t)q * 8 * K3 + (t) * 64,                       \
                  (_Float16*)(smem + (c) * 32768) + (w * 32 + q * 8) * 64);  \
      gload_lds16(gB + (int64_t)q * 8 * K3 + (t) * 64,                       \
                  (_Float16*)(smem + (c) * 32768 + 16384) +                  \
                      (w * 32 + q * 8) * 64);                                \
    }                                                                        \
  } while (0)

  STAGE(0, 0);  // 8 loads/thread outstanding

  for (int t = 0; t < 4; ++t) {
    const int cur = t & 1;
    if (t < 3) {
      STAGE(cur ^ 1, t + 1);  // +8 -> 16 outstanding
      asm volatile("s_waitcnt vmcnt(8)" ::: "memory");  // stage(t) complete
    } else {
      asm volatile("s_waitcnt vmcnt(0)" ::: "memory");
    }
    __builtin_amdgcn_s_barrier();          // all waves' stage(t) visible
    __builtin_amdgcn_sched_barrier(0);
    const _Float16* At = (const _Float16*)(smem + cur * 32768);
    const _Float16* Bt = (const _Float16*)(smem + cur * 32768 + 16384);
#pragma unroll
    for (int kk = 0; kk < 2; ++kk) {
      f16x8 af[4], bf[4];
#pragma unroll
      for (int i = 0; i < 4; ++i)
        af[i] = *(const f16x8*)(At + (am + i * 16 + fr) * 64 +
                                (((kk * 4 + g) ^ (fr & 7)) * 8));
#pragma unroll
      for (int i = 0; i < 4; ++i)
        bf[i] = *(const f16x8*)(Bt + (bn + i * 16 + fr) * 64 +
                                (((kk * 4 + g) ^ (fr & 7)) * 8));
#pragma unroll
      for (int i = 0; i < 4; ++i)
#pragma unroll
        for (int j = 0; j < 4; ++j)
          acc[i][j] = __builtin_amdgcn_mfma_f32_16x16x32_f16(af[i], bf[j], acc[i][j], 0, 0, 0);
    }
    __builtin_amdgcn_sched_barrier(0);
    __builtin_amdgcn_s_barrier();          // reads of buf[cur] done -> safe to overwrite
  }

  // ---- epilogue: per m-chunk q, transpose 32x128 f32 through LDS, then
  // dwordx4 NT stores: each thread writes 16B; one 512B row-segment is a
  // SINGLE contiguous wave-half run (7 full + 2 partial lines, vs 4 partials
  // with the old 4B/lane stores).
  float biasj[4];
#pragma unroll
  for (int j = 0; j < 4; ++j) {
    const int gn = n0 + bn + j * 16 + fr;
    biasj[j] = (gn < VOCAB) ? out_b[gn] : 0.f;
  }
  float* L = (float*)smem;  // [32][132] padded
#pragma unroll
  for (int q = 0; q < 4; ++q) {
#pragma unroll
    for (int j = 0; j < 4; ++j) {
      const int lcol = bn + j * 16 + fr;
#pragma unroll
      for (int r = 0; r < 4; ++r) {
        const int lrow = (w >> 1) * 16 + g * 4 + r;
        L[lrow * 132 + lcol] = acc[q][j][r] + biasj[j];
      }
    }
    __syncthreads();
    // store: 4 passes x (8 rows x 512B); thread -> row tid>>5, colq (tid&31)*4
#pragma unroll
    for (int pass = 0; pass < 4; ++pass) {
      const int lr = pass * 8 + (tid >> 5);
      const int colq = (tid & 31) * 4;
      const int gm = m0 + (lr >> 4) * 64 + q * 16 + (lr & 15);
      const int gcol = n0 + colq;
      const f32x4 v = *(const f32x4*)&L[lr * 132 + colq];
      float* cp = C + (int64_t)gm * VOCAB + gcol;
      if (gcol + 4 <= VOCAB) {
        __builtin_nontemporal_store(v, (f32x4*)cp);
      } else {
#pragma unroll
        for (int e = 0; e < 4; ++e)
          if (gcol + e < VOCAB) __builtin_nontemporal_store(v[e], cp + e);
      }
    }
    __syncthreads();
  }
#undef STAGE
}

extern "C" void kernel_launch(void* const* d_in, const int* in_sizes, int n_in,
                              void* d_out, int out_size, void* d_ws, size_t ws_size,
                              hipStream_t stream) {
  const int* tokens = (const int*)d_in[0];
  const float* embedding = (const float*)d_in[1];
  const float* proj_W = (const float*)d_in[2];
  const float* proj_b = (const float*)d_in[3];
  const float* child_W = (const float*)d_in[4];
  const float* child_b = (const float*)d_in[5];
  const float* sib_emb = (const float*)d_in[6];
  const float* depth_emb = (const float*)d_in[7];
  const float* pol_W1 = (const float*)d_in[8];
  const float* pol_b1 = (const float*)d_in[9];
  const float* pol_w2 = (const float*)d_in[10];
  const float* pol_b2 = (const float*)d_in[11];
  const float* out_W = (const float*)d_in[12];
  const float* out_b = (const float*)d_in[13];
  float* C = (float*)d_out;
  char* ws = (char*)d_ws;
  _Float16* B2 = (_Float16*)ws;                              // 50304*256*2 = 25,755,648 B
  _Float16* A2 = (_Float16*)(ws + 25755648);                 // 4096*256*2  =  2,097,152 B
  float* sibproj = (float*)(ws + 27852800);                  // 4 KB
  float* WT = (float*)(ws + 27856896);                       // 3*256*256*4 = 786,432 B

  k_tr<<<48, 256, 0, stream>>>(proj_W, pol_W1, child_W, WT);
  k_sib<<<4, 256, 0, stream>>>(WT, sib_emb, sibproj);
  k_conv<<<2048, 256, 0, stream>>>(out_W, B2);
  k_pooled<<<256, 256, 0, stream>>>(tokens, embedding, WT, proj_b, child_b,
                                    sib_emb, depth_emb, pol_b1,
                                    pol_w2, pol_b2, sibproj, A2);
  k_gemm<<<12576, 256, 0, stream>>>(A2, B2, out_b, C);
}

// Round 13
// 405.762 us; speedup vs baseline: 1.5666x; 1.0525x over previous
//
#include <hip/hip_runtime.h>
#include <stdint.h>

#define VOCAB 50257
#define NP    50304      // padded vocab = 393*128
#define H     256
#define BS    4096       // B*S tokens
#define K3    256        // single-f16 K
#define SIB   0.0625f    // 1/sqrt(256)

typedef __attribute__((ext_vector_type(8))) _Float16 f16x8;
typedef __attribute__((ext_vector_type(4))) float f32x4;

__device__ __forceinline__ void gload_lds16(const void* g, void* l) {
  __builtin_amdgcn_global_load_lds(
      (const __attribute__((address_space(1))) void*)g,
      (__attribute__((address_space(3))) void*)l, 16, 0, 0);
}

// ---------------- transpose proj_W, pol_W1, child_W -> WT[3][256][256] (WT[m][e][h])
__global__ __launch_bounds__(256) void k_tr(const float* __restrict__ pW,
                                            const float* __restrict__ qW,
                                            const float* __restrict__ cW,
                                            float* __restrict__ WT) {
  __shared__ float T[64][65];
  const int blk = blockIdx.x;           // 48 = 3 matrices x 16 tiles
  const int m = blk >> 4, t = blk & 15;
  const float* src = (m == 0) ? pW : (m == 1) ? qW : cW;
  float* dst = WT + m * 65536;
  const int tr = (t >> 2) * 64, tc = (t & 3) * 64;
  const int r = threadIdx.x >> 6, c = threadIdx.x & 63;
#pragma unroll
  for (int i = 0; i < 16; ++i) {
    const int row = r * 16 + i;
    T[row][c] = src[(tr + row) * H + tc + c];
  }
  __syncthreads();
#pragma unroll
  for (int i = 0; i < 16; ++i) {
    const int row = r * 16 + i;
    dst[(tc + row) * H + tr + c] = T[c][row];
  }
}

// ---------------- sib projections via WT (coalesced): polT@sib0/1, childT@sib0/1
__global__ __launch_bounds__(256) void k_sib(const float* __restrict__ WT,
                                             const float* __restrict__ sib_emb,
                                             float* __restrict__ sibproj) {
  const int b = blockIdx.x;  // 0..3
  const float* Wt = WT + ((b < 2) ? 65536 : 131072);
  const float* v = sib_emb + (b & 1) * H;
  const int h = threadIdx.x;
  float acc = 0.f;
  for (int e4 = 0; e4 < 64; ++e4) {
    const float4 s = *(const float4*)(v + e4 * 4);
    acc += Wt[(e4 * 4 + 0) * H + h] * s.x;
    acc += Wt[(e4 * 4 + 1) * H + h] * s.y;
    acc += Wt[(e4 * 4 + 2) * H + h] * s.z;
    acc += Wt[(e4 * 4 + 3) * H + h] * s.w;
  }
  sibproj[b * H + h] = acc;
}

// ---------------- out_W f32 -> f16 [NP][256] (pad rows zero)
__global__ __launch_bounds__(256) void k_conv(const float* __restrict__ W,
                                              _Float16* __restrict__ B2) {
  const int64_t nit = (int64_t)NP * 32;  // 8 f16 per iter
  for (int64_t i = (int64_t)blockIdx.x * blockDim.x + threadIdx.x; i < nit;
       i += (int64_t)gridDim.x * blockDim.x) {
    const int v = (int)(i >> 5);
    const int h8 = ((int)i & 31) * 8;
    float4 w0, w1;
    if (v < VOCAB) {
      w0 = *(const float4*)(W + (int64_t)v * H + h8);
      w1 = *(const float4*)(W + (int64_t)v * H + h8 + 4);
    } else {
      w0 = make_float4(0.f, 0.f, 0.f, 0.f);
      w1 = w0;
    }
    _Float16 o[8] = {(_Float16)w0.x, (_Float16)w0.y, (_Float16)w0.z, (_Float16)w0.w,
                     (_Float16)w1.x, (_Float16)w1.y, (_Float16)w1.z, (_Float16)w1.w};
    *(f16x8*)(B2 + (int64_t)v * K3 + h8) = *(f16x8*)o;
  }
}

// ---------------- per-token tree -> pooled -> A2 (f16 [4096][256])
#define MATVEC_T(WTp, SRC, ACC)                                                   \
  do {                                                                            \
    _Pragma("unroll") for (int j = 0; j < 4; ++j)                                 \
        _Pragma("unroll") for (int tt = 0; tt < 4; ++tt) ACC[j][tt] = 0.f;        \
    _Pragma("unroll 2") for (int e4 = 0; e4 < 64; ++e4) {                         \
      float4 s4[4];                                                               \
      _Pragma("unroll") for (int tt = 0; tt < 4; ++tt)                            \
          s4[tt] = *(const float4*)&SRC[tg * 4 + tt][e4 * 4];                     \
      _Pragma("unroll") for (int u = 0; u < 4; ++u) {                             \
        const int e = e4 * 4 + u;                                                 \
        float wt[4];                                                              \
        _Pragma("unroll") for (int j = 0; j < 4; ++j)                             \
            wt[j] = (WTp)[e * H + hg + 64 * j];                                   \
        _Pragma("unroll") for (int j = 0; j < 4; ++j)                             \
            _Pragma("unroll") for (int tt = 0; tt < 4; ++tt)                      \
                ACC[j][tt] += wt[j] * ((const float*)&s4[tt])[u];                 \
      }                                                                           \
    }                                                                             \
  } while (0)

#define REDUCE_TO_X(slot)                                                \
  do {                                                                   \
    const int rt = tid >> 4, rl = tid & 15;                              \
    float part = 0.f;                                                    \
    _Pragma("unroll") for (int i = 0; i < 16; ++i) part +=               \
        ZW[rt][rl + 16 * i];                                             \
    part += __shfl_xor(part, 1, 16);                                     \
    part += __shfl_xor(part, 2, 16);                                     \
    part += __shfl_xor(part, 4, 16);                                     \
    part += __shfl_xor(part, 8, 16);                                     \
    if (rl == 0) X[slot][rt] = part + b2;                                \
  } while (0)

__global__ __launch_bounds__(256) void k_pooled(
    const int* __restrict__ tokens, const float* __restrict__ emb,
    const float* __restrict__ WT, const float* __restrict__ proj_b,
    const float* __restrict__ child_b,
    const float* __restrict__ sib_emb, const float* __restrict__ depth_emb,
    const float* __restrict__ pol_b1,
    const float* __restrict__ pol_w2, const float* __restrict__ pol_b2,
    const float* __restrict__ sibproj, _Float16* __restrict__ A2) {
  __shared__ float IN[16][256];
  __shared__ float H0[16][256];
  __shared__ float B0s[16][256];
  __shared__ float ZW[16][264];
  __shared__ float X[3][16];
  __shared__ int TOK[16];
  const int tid = threadIdx.x;
  const int hg = tid & 63;   // h = hg + 64*j
  const int tg = tid >> 6;   // tokens tg*4 .. tg*4+3
  const int t0 = blockIdx.x * 16;
  const float b2 = pol_b2[0];
  const float* projT = WT;
  const float* polT = WT + 65536;
  const float* childT = WT + 131072;

  float sibs[4];
#pragma unroll
  for (int j = 0; j < 4; ++j) {
    const int hj = hg + 64 * j;
    sibs[j] = SIB * (sib_emb[hj] + sib_emb[H + hj]);
  }

  if (tid < 16) TOK[tid] = tokens[t0 + tid];
  __syncthreads();
  for (int t = 0; t < 16; ++t) IN[t][tid] = emb[(int64_t)TOK[t] * H + tid];
  __syncthreads();

  float acc[4][4], sum[4][4];

  // h0 = proj_W @ emb + proj_b
  MATVEC_T(projT, IN, acc);
#pragma unroll
  for (int j = 0; j < 4; ++j) {
    const int hj = hg + 64 * j;
    const float pb = proj_b[hj];
#pragma unroll
    for (int tt = 0; tt < 4; ++tt) {
      const float h0v = acc[j][tt] + pb;
      H0[tg * 4 + tt][hj] = h0v;
      sum[j][tt] = h0v;
    }
  }
  __syncthreads();

  // depth-0 policy
  MATVEC_T(polT, H0, acc);
#pragma unroll
  for (int j = 0; j < 4; ++j) {
    const int hj = hg + 64 * j;
    const float pb1 = pol_b1[hj], de0 = depth_emb[hj], w2 = pol_w2[hj];
#pragma unroll
    for (int tt = 0; tt < 4; ++tt) {
      const float z = tanhf(acc[j][tt] + pb1 + de0);
      ZW[tg * 4 + tt][hj] = z * w2;
    }
  }
  __syncthreads();
  REDUCE_TO_X(0);
  __syncthreads();

  // depth-0 children base
  MATVEC_T(childT, H0, acc);
#pragma unroll
  for (int j = 0; j < 4; ++j) {
    const int hj = hg + 64 * j;
    const float cb = child_b[hj];
#pragma unroll
    for (int tt = 0; tt < 4; ++tt) {
      const float base0 = tanhf(acc[j][tt] + cb);
      B0s[tg * 4 + tt][hj] = base0;
      const float g0 = (X[0][tg * 4 + tt] >= 0.f) ? 1.f : 0.f;
      sum[j][tt] += g0 * (2.f * base0 + sibs[j]);
    }
  }
  __syncthreads();

  // depth-1 policy: polW@base (+ precomputed polW@sib_k)
  float accP[4][4];
  MATVEC_T(polT, B0s, accP);
#pragma unroll
  for (int k = 0; k < 2; ++k) {
#pragma unroll
    for (int j = 0; j < 4; ++j) {
      const int hj = hg + 64 * j;
      const float pb1 = pol_b1[hj], de1 = depth_emb[H + hj], w2 = pol_w2[hj];
      const float ps = sibproj[k * H + hj];
#pragma unroll
      for (int tt = 0; tt < 4; ++tt) {
        const float z = tanhf(accP[j][tt] + SIB * ps + pb1 + de1);
        ZW[tg * 4 + tt][hj] = z * w2;
      }
    }
    __syncthreads();
    if (k == 0) REDUCE_TO_X(1); else REDUCE_TO_X(2);
    __syncthreads();
  }

  // depth-1 children base + final pooled
  MATVEC_T(childT, B0s, acc);
#pragma unroll
  for (int j = 0; j < 4; ++j) {
    const int hj = hg + 64 * j;
    const float cb = child_b[hj];
    const float cs0 = sibproj[2 * H + hj], cs1 = sibproj[3 * H + hj];
#pragma unroll
    for (int tt = 0; tt < 4; ++tt) {
      const int t = tg * 4 + tt;
      const float g0 = (X[0][t] >= 0.f) ? 1.f : 0.f;
      const float m0 = (g0 > 0.f && X[1][t] >= 0.f) ? 1.f : 0.f;
      const float m1 = (g0 > 0.f && X[2][t] >= 0.f) ? 1.f : 0.f;
      const float bk0 = tanhf(acc[j][tt] + SIB * cs0 + cb);
      const float bk1 = tanhf(acc[j][tt] + SIB * cs1 + cb);
      float s = sum[j][tt] + m0 * (2.f * bk0 + sibs[j]) + m1 * (2.f * bk1 + sibs[j]);
      const float cnt = 1.f + 2.f * g0 + 2.f * (m0 + m1);
      const float pooled = s / (cnt + 1e-8f);
      A2[(int64_t)(t0 + t) * K3 + hj] = (_Float16)pooled;
    }
  }
}

// ---------------- big GEMM (R12 skeleton; ONLY change: n-inner block order)
// xcd owns m-rows xcd*4..xcd*4+3; within XCD local = m_l*393 + n_l, n fastest.
// Time-adjacent blocks (same XCD, ~1us apart) write the SAME 128 rows'
// ADJACENT 512B segments -> misaligned boundary lines complete while still
// in L2, and each row's write stream walks DRAM pages forward.
__global__ __launch_bounds__(256) void k_gemm(const _Float16* __restrict__ A2,
                                              const _Float16* __restrict__ B2,
                                              const float* __restrict__ out_b,
                                              float* __restrict__ C) {
  __shared__ __align__(16) char smem[65536];  // 2 x (At 16KB + Bt 16KB)
  const int tid = threadIdx.x;
  const int lane = tid & 63;
  const int w = tid >> 6;
  const int wg = blockIdx.x;
  const int xcd = wg & 7;
  const int local = wg >> 3;          // [0,1572) = 4 m-rows x 393 n
  const int m_l = local / 393;        // 0..3
  const int n_l = local - m_l * 393;  // 0..392, fastest
  const int m0 = (xcd * 4 + m_l) * 128;
  const int n0 = n_l * 128;
  f32x4 acc[4][4] = {};

  const int rl = lane >> 3;                 // row within 8-row group
  const int gsw = (lane & 7) ^ rl;          // pre-swizzled source granule
  const _Float16* gA = A2 + (int64_t)(m0 + w * 32 + rl) * K3 + gsw * 8;
  const _Float16* gB = B2 + (int64_t)(n0 + w * 32 + rl) * K3 + gsw * 8;

  const int fr = lane & 15;
  const int g = lane >> 4;                  // K-octet within 32-wide MFMA K
  const int am = (w >> 1) * 64;
  const int bn = (w & 1) * 64;

#define STAGE(c, t)                                                          \
  do {                                                                       \
    _Pragma("unroll") for (int q = 0; q < 4; ++q) {                          \
      gload_lds16(gA + (int64_t)q * 8 * K3 + (t) * 64,                       \
                  (_Float16*)(smem + (c) * 32768) + (w * 32 + q * 8) * 64);  \
      gload_lds16(gB + (int64_t)q * 8 * K3 + (t) * 64,                       \
                  (_Float16*)(smem + (c) * 32768 + 16384) +                  \
                      (w * 32 + q * 8) * 64);                                \
    }                                                                        \
  } while (0)

  STAGE(0, 0);  // 8 loads/thread outstanding

  for (int t = 0; t < 4; ++t) {
    const int cur = t & 1;
    if (t < 3) {
      STAGE(cur ^ 1, t + 1);  // +8 -> 16 outstanding
      asm volatile("s_waitcnt vmcnt(8)" ::: "memory");  // stage(t) complete
    } else {
      asm volatile("s_waitcnt vmcnt(0)" ::: "memory");
    }
    __builtin_amdgcn_s_barrier();          // all waves' stage(t) visible
    __builtin_amdgcn_sched_barrier(0);
    const _Float16* At = (const _Float16*)(smem + cur * 32768);
    const _Float16* Bt = (const _Float16*)(smem + cur * 32768 + 16384);
#pragma unroll
    for (int kk = 0; kk < 2; ++kk) {
      f16x8 af[4], bf[4];
#pragma unroll
      for (int i = 0; i < 4; ++i)
        af[i] = *(const f16x8*)(At + (am + i * 16 + fr) * 64 +
                                (((kk * 4 + g) ^ (fr & 7)) * 8));
#pragma unroll
      for (int i = 0; i < 4; ++i)
        bf[i] = *(const f16x8*)(Bt + (bn + i * 16 + fr) * 64 +
                                (((kk * 4 + g) ^ (fr & 7)) * 8));
#pragma unroll
      for (int i = 0; i < 4; ++i)
#pragma unroll
        for (int j = 0; j < 4; ++j)
          acc[i][j] = __builtin_amdgcn_mfma_f32_16x16x32_f16(af[i], bf[j], acc[i][j], 0, 0, 0);
    }
    __builtin_amdgcn_sched_barrier(0);
    __builtin_amdgcn_s_barrier();          // reads of buf[cur] done -> safe to overwrite
  }

  // ---- epilogue: per m-chunk q, transpose 32x128 f32 through LDS, then
  // dwordx4 NT stores (512B contiguous run per 32 lanes).
  float biasj[4];
#pragma unroll
  for (int j = 0; j < 4; ++j) {
    const int gn = n0 + bn + j * 16 + fr;
    biasj[j] = (gn < VOCAB) ? out_b[gn] : 0.f;
  }
  float* L = (float*)smem;  // [32][132] padded
#pragma unroll
  for (int q = 0; q < 4; ++q) {
#pragma unroll
    for (int j = 0; j < 4; ++j) {
      const int lcol = bn + j * 16 + fr;
#pragma unroll
      for (int r = 0; r < 4; ++r) {
        const int lrow = (w >> 1) * 16 + g * 4 + r;
        L[lrow * 132 + lcol] = acc[q][j][r] + biasj[j];
      }
    }
    __syncthreads();
#pragma unroll
    for (int pass = 0; pass < 4; ++pass) {
      const int lr = pass * 8 + (tid >> 5);
      const int colq = (tid & 31) * 4;
      const int gm = m0 + (lr >> 4) * 64 + q * 16 + (lr & 15);
      const int gcol = n0 + colq;
      const f32x4 v = *(const f32x4*)&L[lr * 132 + colq];
      float* cp = C + (int64_t)gm * VOCAB + gcol;
      if (gcol + 4 <= VOCAB) {
        __builtin_nontemporal_store(v, (f32x4*)cp);
      } else {
#pragma unroll
        for (int e = 0; e < 4; ++e)
          if (gcol + e < VOCAB) __builtin_nontemporal_store(v[e], cp + e);
      }
    }
    __syncthreads();
  }
#undef STAGE
}

extern "C" void kernel_launch(void* const* d_in, const int* in_sizes, int n_in,
                              void* d_out, int out_size, void* d_ws, size_t ws_size,
                              hipStream_t stream) {
  const int* tokens = (const int*)d_in[0];
  const float* embedding = (const float*)d_in[1];
  const float* proj_W = (const float*)d_in[2];
  const float* proj_b = (const float*)d_in[3];
  const float* child_W = (const float*)d_in[4];
  const float* child_b = (const float*)d_in[5];
  const float* sib_emb = (const float*)d_in[6];
  const float* depth_emb = (const float*)d_in[7];
  const float* pol_W1 = (const float*)d_in[8];
  const float* pol_b1 = (const float*)d_in[9];
  const float* pol_w2 = (const float*)d_in[10];
  const float* pol_b2 = (const float*)d_in[11];
  const float* out_W = (const float*)d_in[12];
  const float* out_b = (const float*)d_in[13];
  float* C = (float*)d_out;
  char* ws = (char*)d_ws;
  _Float16* B2 = (_Float16*)ws;                              // 50304*256*2 = 25,755,648 B
  _Float16* A2 = (_Float16*)(ws + 25755648);                 // 4096*256*2  =  2,097,152 B
  float* sibproj = (float*)(ws + 27852800);                  // 4 KB
  float* WT = (float*)(ws + 27856896);                       // 3*256*256*4 = 786,432 B

  k_tr<<<48, 256, 0, stream>>>(proj_W, pol_W1, child_W, WT);
  k_sib<<<4, 256, 0, stream>>>(WT, sib_emb, sibproj);
  k_conv<<<2048, 256, 0, stream>>>(out_W, B2);
  k_pooled<<<256, 256, 0, stream>>>(tokens, embedding, WT, proj_b, child_b,
                                    sib_emb, depth_emb, pol_b1,
                                    pol_w2, pol_b2, sibproj, A2);
  k_gemm<<<12576, 256, 0, stream>>>(A2, B2, out_b, C);
}